// Round 7
// baseline (1010.353 us; speedup 1.0000x reference)
//
#include <hip/hip_runtime.h>

typedef __attribute__((ext_vector_type(4))) float f32x4;
typedef __attribute__((ext_vector_type(8))) short s16x8;
typedef unsigned int u32;

#define XDIM 440
#define ODIM 220
#define RPB  32          // rows per block
#define TPB  128         // 2 waves; wave w owns rows [w*16, w*16+16)
#define XSW  52          // xsl row stride (u32): 16B rows, stride%32=20 -> 2-way banks
#define AW   68          // Act row stride (u32): 16B rows, stride%32=4  -> 2-way banks

// ---------- packed split helpers (fp32 -> bf16hi|bf16lo in one u32) ----------
__device__ __forceinline__ u32 cvtpk(float a, float b){
    u32 r; asm("v_cvt_pk_bf16_f32 %0, %1, %2" : "=v"(r) : "v"(a), "v"(b)); return r;
}
__device__ __forceinline__ u32 permb(u32 a, u32 b, u32 s){ return __builtin_amdgcn_perm(a, b, s); }

__device__ __forceinline__ u32 packf(float v){
    u32 h = cvtpk(v, v);                                  // [15:0] = bf16(v)
    float hf = __builtin_bit_cast(float, h << 16);
    u32 lo = cvtpk(v - hf, v - hf);                       // v-hf exact (Sterbenz)
    return permb(h, lo, 0x05040100u);                     // [31:16]=hi [15:0]=lo
}

__device__ __forceinline__ void split8pk(const float* v, s16x8& h, s16x8& l){
    uint4 hu, lu; u32* hp = (u32*)&hu; u32* lp = (u32*)&lu;
    #pragma unroll
    for (int j = 0; j < 4; ++j){
        u32 hk = cvtpk(v[2*j], v[2*j+1]);
        float h0 = __builtin_bit_cast(float, hk << 16);
        float h1 = __builtin_bit_cast(float, hk & 0xFFFF0000u);
        lp[j] = cvtpk(v[2*j] - h0, v[2*j+1] - h1);
        hp[j] = hk;
    }
    h = __builtin_bit_cast(s16x8, hu);
    l = __builtin_bit_cast(s16x8, lu);
}

// 8 packed u32 -> (hi, lo) s16x8 fragments, 1 v_perm per output reg
__device__ __forceinline__ void buildfrag(const u32* p, s16x8& h, s16x8& l){
    uint4 U0 = *(const uint4*)p;
    uint4 U1 = *(const uint4*)(p + 4);
    u32 u0=U0.x,u1=U0.y,u2=U0.z,u3=U0.w,u4=U1.x,u5=U1.y,u6=U1.z,u7=U1.w;
    uint4 hu, lu;
    hu.x = permb(u1,u0,0x07060302u); lu.x = permb(u1,u0,0x05040100u);
    hu.y = permb(u3,u2,0x07060302u); lu.y = permb(u3,u2,0x05040100u);
    hu.z = permb(u5,u4,0x07060302u); lu.z = permb(u5,u4,0x05040100u);
    hu.w = permb(u7,u6,0x07060302u); lu.w = permb(u7,u6,0x05040100u);
    h = __builtin_bit_cast(s16x8, hu);
    l = __builtin_bit_cast(s16x8, lu);
}

__device__ __forceinline__ s16x8 ld8u(const unsigned short* p){ return *(const s16x8*)p; }

// D += A*B, split-bf16: AhBh + AhBl + AlBh (AlBl dropped, ~2^-18)
__device__ __forceinline__ f32x4 mm3(s16x8 ah, s16x8 al, s16x8 bh, s16x8 bl, f32x4 c){
    c = __builtin_amdgcn_mfma_f32_16x16x32_bf16(ah, bh, c, 0, 0, 0);
    c = __builtin_amdgcn_mfma_f32_16x16x32_bf16(ah, bl, c, 0, 0, 0);
    c = __builtin_amdgcn_mfma_f32_16x16x32_bf16(al, bh, c, 0, 0, 0);
    return c;
}

// ---------- weight prep: split to bf16 hi/lo, pad to [240][64] ----------
// rows: [0..47]=bW1 [48..95]=bW2 [96..111]=bW3 [112..159]=sW1 [160..207]=sW2 [208..239]=sW3
__device__ __forceinline__ unsigned short bf_rne(float f){
    unsigned u = __builtin_bit_cast(unsigned, f);
    return (unsigned short)((u + 0x7FFFu + ((u >> 16) & 1u)) >> 16);
}

__global__ void prep_w(const float* __restrict__ bW1, const float* __restrict__ bW2,
                       const float* __restrict__ bW3, const float* __restrict__ sW1,
                       const float* __restrict__ sW2, const float* __restrict__ sW3,
                       const float* __restrict__ bb1, const float* __restrict__ bb2,
                       const float* __restrict__ bb3, const float* __restrict__ sb1,
                       const float* __restrict__ sb2, const float* __restrict__ sb3,
                       unsigned short* __restrict__ WH, unsigned short* __restrict__ WL,
                       float* __restrict__ BIAS)
{
    int i = blockIdx.x * 256 + threadIdx.x;
    if (i < 15360) {
        int n = i >> 6, k = i & 63;
        float w = 0.f;
        if      (n < 48)  { int r = n;     if (r < 40 && k < 40) w = bW1[r*40+k]; }
        else if (n < 96)  { int r = n-48;  if (r < 40 && k < 40) w = bW2[r*40+k]; }
        else if (n < 112) { int r = n-96;  if (r < 10 && k < 40) w = bW3[r*40+k]; }
        else if (n < 160) { int r = n-112; if (r < 41 && k < 41) w = sW1[r*41+k]; }
        else if (n < 208) { int r = n-160; if (r < 41 && k < 41) w = sW2[r*41+k]; }
        else              { int r = n-208; if (r < 22 && k < 41) w = sW3[r*41+k]; }
        unsigned short h = bf_rne(w);
        float hf = __builtin_bit_cast(float, ((unsigned)h) << 16);
        WH[i] = h; WL[i] = bf_rne(w - hf);
    } else if (i < 15600) {
        int n = i - 15360;
        float b;
        if      (n < 48)  b = (n     < 40) ? bb1[n]     : 0.f;
        else if (n < 96)  b = (n-48  < 40) ? bb2[n-48]  : 0.f;
        else if (n < 112) b = (n-96  < 10) ? bb3[n-96]  : -1e30f;
        else if (n < 160) b = (n-112 < 41) ? sb1[n-112] : 0.f;
        else if (n < 208) b = (n-160 < 41) ? sb2[n-160] : 0.f;
        else              b = (n-208 < 22) ? sb3[n-208] : -1e30f;
        BIAS[n] = b;
    }
}

// ---------- slot staging: 32 rows x 40 cols, coalesced float4, pre-split ----------
__device__ __forceinline__ void stage_load(const float* __restrict__ x, int R0, int S,
                                           int tid, float4* pf){
    #pragma unroll
    for (int it = 0; it < 3; ++it){
        int f = tid + TPB*it;
        if (f < 320){
            int r = f/10, c4 = f - r*10;
            pf[it] = *(const float4*)(x + (size_t)(R0+r)*XDIM + 40 + S*40 + c4*4);
        }
    }
}
__device__ __forceinline__ void stage_write(u32 (*xb)[XSW], const float* iap, int S,
                                            int tid, const float4* pf){
    #pragma unroll
    for (int it = 0; it < 3; ++it){
        int f = tid + TPB*it;
        if (f < 320){
            int r = f/10, c4 = f - r*10;
            uint4 pk;
            pk.x = packf(pf[it].x); pk.y = packf(pf[it].y);
            pk.z = packf(pf[it].z); pk.w = packf(pf[it].w);
            *(uint4*)&xb[r][c4*4] = pk;
        }
    }
    if (tid < RPB) xb[tid][40] = packf(iap[tid*10 + S]);   // iab input (k=40)
}

__global__ __launch_bounds__(TPB, 4) void ran2(
    const float* __restrict__ x,
    const unsigned short* __restrict__ WH,
    const unsigned short* __restrict__ WL,
    const float* __restrict__ BIAS,
    float* __restrict__ out)
{
    __shared__ u32   xsl[2][RPB][XSW];   // per-slot inputs, packed split, dbuf (13.0 KB)
    __shared__ u32   Act[RPB][AW];       // activations, packed split (8.5 KB)
    __shared__ float ia[RPB][10];        // big-net softmax (1.25 KB)
    // total 23.3 KB -> 6-7 blocks/CU (vs r5's 51.7 KB -> 3)

    const int tid  = threadIdx.x;
    const int l    = tid & 63;
    const int w    = tid >> 6;
    const int q    = l >> 4;
    const int li   = l & 15;
    const int w16  = w * 16;
    const int R0   = blockIdx.x * RPB;
    const int arow = w16 + li;           // this lane's A-fragment row (local)

    // one-time zero of pad regions (xsl cols 40..51 both buffers; Act cols 48..67)
    for (int i = tid; i < 2*RPB*(XSW-40); i += TPB){
        int b = i / (RPB*(XSW-40)), k = i % (RPB*(XSW-40));
        xsl[b][k/(XSW-40)][40 + k%(XSW-40)] = 0u;
    }
    for (int i = tid; i < RPB*(AW-48); i += TPB)
        Act[i/(AW-48)][48 + i%(AW-48)] = 0u;
    __syncthreads();

    // ================= BIG NET (Act is wave-private: no barriers) =================
    {   // L1: x[:,0:40] -> Act
        s16x8 th[3][2], tl[3][2]; float tb[3];
        #pragma unroll
        for (int nt=0; nt<3; ++nt){
            tb[nt] = BIAS[nt*16+li];
            #pragma unroll
            for (int ks=0; ks<2; ++ks){
                th[nt][ks] = ld8u(WH + (nt*16+li)*64 + ks*32 + q*8);
                tl[nt][ks] = ld8u(WL + (nt*16+li)*64 + ks*32 + q*8);
            }
        }
        const float* xp = x + (size_t)(R0 + arow) * XDIM;
        float a0[8], a1[8];
        *(float4*)(a0)   = *(const float4*)(xp + q*8);
        *(float4*)(a0+4) = *(const float4*)(xp + q*8 + 4);
        if (q == 0){
            *(float4*)(a1)   = *(const float4*)(xp + 32);
            *(float4*)(a1+4) = *(const float4*)(xp + 36);
        } else {
            #pragma unroll
            for (int j=0;j<8;++j) a1[j] = 0.f;
        }
        s16x8 ah0,al0,ah1,al1;
        split8pk(a0, ah0, al0); split8pk(a1, ah1, al1);
        #pragma unroll
        for (int nt=0; nt<3; ++nt){
            f32x4 acc = {tb[nt],tb[nt],tb[nt],tb[nt]};
            acc = mm3(ah0,al0, th[nt][0], tl[nt][0], acc);
            acc = mm3(ah1,al1, th[nt][1], tl[nt][1], acc);
            #pragma unroll
            for (int r=0;r<4;++r)
                Act[w16+q*4+r][nt*16+li] = packf(fmaxf(acc[r],0.f));
        }
    }
    {   // L2: Act -> Act
        s16x8 th[3][2], tl[3][2]; float tb[3];
        #pragma unroll
        for (int nt=0; nt<3; ++nt){
            tb[nt] = BIAS[48+nt*16+li];
            #pragma unroll
            for (int ks=0; ks<2; ++ks){
                th[nt][ks] = ld8u(WH + (48+nt*16+li)*64 + ks*32 + q*8);
                tl[nt][ks] = ld8u(WL + (48+nt*16+li)*64 + ks*32 + q*8);
            }
        }
        s16x8 ah0,al0,ah1,al1;
        const u32* ap = &Act[arow][0];
        buildfrag(ap + q*8, ah0, al0);
        buildfrag(ap + 32 + q*8, ah1, al1);
        #pragma unroll
        for (int nt=0; nt<3; ++nt){
            f32x4 acc = {tb[nt],tb[nt],tb[nt],tb[nt]};
            acc = mm3(ah0,al0, th[nt][0], tl[nt][0], acc);
            acc = mm3(ah1,al1, th[nt][1], tl[nt][1], acc);
            #pragma unroll
            for (int r=0;r<4;++r)
                Act[w16+q*4+r][nt*16+li] = packf(fmaxf(acc[r],0.f));
        }
    }
    {   // L3 + softmax -> ia
        s16x8 th[2], tl[2]; float tb = BIAS[96+li];
        th[0] = ld8u(WH + (96+li)*64 + q*8);      tl[0] = ld8u(WL + (96+li)*64 + q*8);
        th[1] = ld8u(WH + (96+li)*64 + 32 + q*8); tl[1] = ld8u(WL + (96+li)*64 + 32 + q*8);
        s16x8 ah0,al0,ah1,al1;
        const u32* ap = &Act[arow][0];
        buildfrag(ap + q*8, ah0, al0);
        buildfrag(ap + 32 + q*8, ah1, al1);
        f32x4 acc = {tb,tb,tb,tb};
        acc = mm3(ah0,al0, th[0], tl[0], acc);
        acc = mm3(ah1,al1, th[1], tl[1], acc);
        #pragma unroll
        for (int r=0;r<4;++r){
            float v = acc[r];
            float m = v;
            m = fmaxf(m, __shfl_xor(m,1)); m = fmaxf(m, __shfl_xor(m,2));
            m = fmaxf(m, __shfl_xor(m,4)); m = fmaxf(m, __shfl_xor(m,8));
            float e = __expf(v - m);
            float sum = e;
            sum += __shfl_xor(sum,1); sum += __shfl_xor(sum,2);
            sum += __shfl_xor(sum,4); sum += __shfl_xor(sum,8);
            float p = __fdividef(e, sum);
            if (li < 10) ia[w16+q*4+r][li] = p;
        }
    }
    __syncthreads();   // ia visible (stage reads it cross-wave)

    // hoist small-net weights (compiler may demote to L1-hot reloads; either is fine)
    s16x8 sh[8][2], sl[8][2]; float sb[8];
    {
        const int base[8] = {112,128,144, 160,176,192, 208,224};
        #pragma unroll
        for (int t2=0;t2<8;++t2){
            int n = base[t2] + li;
            sb[t2] = BIAS[n];
            #pragma unroll
            for (int ks=0;ks<2;++ks){
                sh[t2][ks] = ld8u(WH + n*64 + ks*32 + q*8);
                sl[t2][ks] = ld8u(WL + n*64 + ks*32 + q*8);
            }
        }
    }

    // stage slot 0
    {
        float4 pf[3];
        stage_load(x, R0, 0, tid, pf);
        stage_write(xsl[0], &ia[0][0], 0, tid, pf);
    }
    __syncthreads();

    // ================= SMALL NET: 10 slots, 1 barrier each =================
    int cur = 0;
    #pragma unroll 1
    for (int s = 0; s < 10; ++s){
        float4 pf[3];
        if (s < 9) stage_load(x, R0, s+1, tid, pf);      // early issue (T14)

        // ---- L1: xsl[cur] -> Act ----
        {
            s16x8 ah0,al0,ah1,al1;
            const u32* xr = &xsl[cur][arow][0];
            buildfrag(xr + q*8, ah0, al0);
            if (q < 2) buildfrag(xr + 32 + q*8, ah1, al1);
            else { uint4 z = {0,0,0,0}; ah1 = __builtin_bit_cast(s16x8, z); al1 = ah1; }
            #pragma unroll
            for (int nt=0; nt<3; ++nt){
                f32x4 acc = {sb[nt],sb[nt],sb[nt],sb[nt]};
                acc = mm3(ah0,al0, sh[nt][0], sl[nt][0], acc);
                acc = mm3(ah1,al1, sh[nt][1], sl[nt][1], acc);
                #pragma unroll
                for (int r=0;r<4;++r)
                    Act[w16+q*4+r][nt*16+li] = packf(fmaxf(acc[r],0.f));
            }
        }
        // write next slot's tile into the free buffer (hidden under compute)
        if (s < 9) stage_write(xsl[cur^1], &ia[0][0], s+1, tid, pf);

        // ---- L2: Act -> Act ----
        {
            s16x8 ah0,al0,ah1,al1;
            const u32* ap = &Act[arow][0];
            buildfrag(ap + q*8, ah0, al0);
            buildfrag(ap + 32 + q*8, ah1, al1);
            #pragma unroll
            for (int nt=0; nt<3; ++nt){
                f32x4 acc = {sb[3+nt],sb[3+nt],sb[3+nt],sb[3+nt]};
                acc = mm3(ah0,al0, sh[3+nt][0], sl[3+nt][0], acc);
                acc = mm3(ah1,al1, sh[3+nt][1], sl[3+nt][1], acc);
                #pragma unroll
                for (int r=0;r<4;++r)
                    Act[w16+q*4+r][nt*16+li] = packf(fmaxf(acc[r],0.f));
            }
        }
        // ---- L3 + softmax * iab -> direct global store ----
        {
            s16x8 ah0,al0,ah1,al1;
            const u32* ap = &Act[arow][0];
            buildfrag(ap + q*8, ah0, al0);
            buildfrag(ap + 32 + q*8, ah1, al1);
            f32x4 a6 = {sb[6],sb[6],sb[6],sb[6]};
            f32x4 a7 = {sb[7],sb[7],sb[7],sb[7]};
            a6 = mm3(ah0,al0, sh[6][0], sl[6][0], a6);
            a6 = mm3(ah1,al1, sh[6][1], sl[6][1], a6);
            a7 = mm3(ah0,al0, sh[7][0], sl[7][0], a7);
            a7 = mm3(ah1,al1, sh[7][1], sl[7][1], a7);
            #pragma unroll
            for (int r=0;r<4;++r){
                float v0 = a6[r], v1 = a7[r];
                float m = fmaxf(v0, v1);
                m = fmaxf(m, __shfl_xor(m,1)); m = fmaxf(m, __shfl_xor(m,2));
                m = fmaxf(m, __shfl_xor(m,4)); m = fmaxf(m, __shfl_xor(m,8));
                float e0 = __expf(v0 - m), e1 = __expf(v1 - m);
                float sum = e0 + e1;
                sum += __shfl_xor(sum,1); sum += __shfl_xor(sum,2);
                sum += __shfl_xor(sum,4); sum += __shfl_xor(sum,8);
                int lr = w16 + q*4 + r;
                float sc = __fdividef(ia[lr][s], sum);
                float* op = out + (size_t)(R0 + lr) * ODIM + s*22;
                op[li] = e0 * sc;
                if (li < 6) op[16 + li] = e1 * sc;
            }
        }
        __syncthreads();   // stage visible + Act epoch boundary
        cur ^= 1;
    }
}

extern "C" void kernel_launch(void* const* d_in, const int* in_sizes, int n_in,
                              void* d_out, int out_size, void* d_ws, size_t ws_size,
                              hipStream_t stream)
{
    (void)n_in; (void)out_size; (void)ws_size;
    const float* x   = (const float*)d_in[0];
    const float* bW1 = (const float*)d_in[1];
    const float* bb1 = (const float*)d_in[2];
    const float* bW2 = (const float*)d_in[3];
    const float* bb2 = (const float*)d_in[4];
    const float* bW3 = (const float*)d_in[5];
    const float* bb3 = (const float*)d_in[6];
    const float* sW1 = (const float*)d_in[7];
    const float* sb1 = (const float*)d_in[8];
    const float* sW2 = (const float*)d_in[9];
    const float* sb2 = (const float*)d_in[10];
    const float* sW3 = (const float*)d_in[11];
    const float* sb3 = (const float*)d_in[12];
    float* outp = (float*)d_out;

    unsigned short* WH = (unsigned short*)d_ws;
    unsigned short* WL = WH + 15360;
    float* BIAS = (float*)(WH + 30720);

    prep_w<<<61, 256, 0, stream>>>(bW1, bW2, bW3, sW1, sW2, sW3,
                                   bb1, bb2, bb3, sb1, sb2, sb3, WH, WL, BIAS);

    const int rows = in_sizes[0] / XDIM;            // 262144
    ran2<<<rows / RPB, TPB, 0, stream>>>(x, WH, WL, BIAS, outp);
}

// Round 9
// 739.620 us; speedup vs baseline: 1.3660x; 1.3660x over previous
//
#include <hip/hip_runtime.h>

typedef __attribute__((ext_vector_type(4))) float f32x4;
typedef __attribute__((ext_vector_type(8))) short s16x8;
typedef unsigned int u32;

#define XDIM 440
#define ODIM 220
#define RPB  32          // rows per block
#define TPB  128         // 2 waves; wave w owns rows [w*16, w*16+16)
#define XSW  52          // xsl row stride (u32)
#define AW   68          // Act row stride (u32)

// ---------- packed split helpers (fp32 -> bf16hi|bf16lo in one u32) ----------
__device__ __forceinline__ u32 cvtpk(float a, float b){
    u32 r; asm("v_cvt_pk_bf16_f32 %0, %1, %2" : "=v"(r) : "v"(a), "v"(b)); return r;
}
__device__ __forceinline__ u32 permb(u32 a, u32 b, u32 s){ return __builtin_amdgcn_perm(a, b, s); }

__device__ __forceinline__ u32 packf(float v){
    u32 h = cvtpk(v, v);                                  // [15:0] = bf16(v)
    float hf = __builtin_bit_cast(float, h << 16);
    u32 lo = cvtpk(v - hf, v - hf);                       // v-hf exact (Sterbenz)
    return permb(h, lo, 0x05040100u);                     // [31:16]=hi [15:0]=lo
}

__device__ __forceinline__ void split8pk(const float* v, s16x8& h, s16x8& l){
    uint4 hu, lu; u32* hp = (u32*)&hu; u32* lp = (u32*)&lu;
    #pragma unroll
    for (int j = 0; j < 4; ++j){
        u32 hk = cvtpk(v[2*j], v[2*j+1]);
        float h0 = __builtin_bit_cast(float, hk << 16);
        float h1 = __builtin_bit_cast(float, hk & 0xFFFF0000u);
        lp[j] = cvtpk(v[2*j] - h0, v[2*j+1] - h1);
        hp[j] = hk;
    }
    h = __builtin_bit_cast(s16x8, hu);
    l = __builtin_bit_cast(s16x8, lu);
}

// 8 packed u32 -> (hi, lo) s16x8 fragments, 1 v_perm per output reg
__device__ __forceinline__ void buildfrag(const u32* p, s16x8& h, s16x8& l){
    uint4 U0 = *(const uint4*)p;
    uint4 U1 = *(const uint4*)(p + 4);
    u32 u0=U0.x,u1=U0.y,u2=U0.z,u3=U0.w,u4=U1.x,u5=U1.y,u6=U1.z,u7=U1.w;
    uint4 hu, lu;
    hu.x = permb(u1,u0,0x07060302u); lu.x = permb(u1,u0,0x05040100u);
    hu.y = permb(u3,u2,0x07060302u); lu.y = permb(u3,u2,0x05040100u);
    hu.z = permb(u5,u4,0x07060302u); lu.z = permb(u5,u4,0x05040100u);
    hu.w = permb(u7,u6,0x07060302u); lu.w = permb(u7,u6,0x05040100u);
    h = __builtin_bit_cast(s16x8, hu);
    l = __builtin_bit_cast(s16x8, lu);
}

__device__ __forceinline__ s16x8 ld8u(const unsigned short* p){ return *(const s16x8*)p; }

// D += A*B, split-bf16: AhBh + AhBl + AlBh (AlBl dropped, ~2^-18)
__device__ __forceinline__ f32x4 mm3(s16x8 ah, s16x8 al, s16x8 bh, s16x8 bl, f32x4 c){
    c = __builtin_amdgcn_mfma_f32_16x16x32_bf16(ah, bh, c, 0, 0, 0);
    c = __builtin_amdgcn_mfma_f32_16x16x32_bf16(ah, bl, c, 0, 0, 0);
    c = __builtin_amdgcn_mfma_f32_16x16x32_bf16(al, bh, c, 0, 0, 0);
    return c;
}

// ---------- weight prep: split to bf16 hi/lo, pad to [240][64] ----------
// rows: [0..47]=bW1 [48..95]=bW2 [96..111]=bW3 [112..159]=sW1 [160..207]=sW2 [208..239]=sW3
__device__ __forceinline__ unsigned short bf_rne(float f){
    unsigned u = __builtin_bit_cast(unsigned, f);
    return (unsigned short)((u + 0x7FFFu + ((u >> 16) & 1u)) >> 16);
}

__global__ void prep_w(const float* __restrict__ bW1, const float* __restrict__ bW2,
                       const float* __restrict__ bW3, const float* __restrict__ sW1,
                       const float* __restrict__ sW2, const float* __restrict__ sW3,
                       const float* __restrict__ bb1, const float* __restrict__ bb2,
                       const float* __restrict__ bb3, const float* __restrict__ sb1,
                       const float* __restrict__ sb2, const float* __restrict__ sb3,
                       unsigned short* __restrict__ WH, unsigned short* __restrict__ WL,
                       float* __restrict__ BIAS)
{
    int i = blockIdx.x * 256 + threadIdx.x;
    if (i < 15360) {
        int n = i >> 6, k = i & 63;
        float w = 0.f;
        if      (n < 48)  { int r = n;     if (r < 40 && k < 40) w = bW1[r*40+k]; }
        else if (n < 96)  { int r = n-48;  if (r < 40 && k < 40) w = bW2[r*40+k]; }
        else if (n < 112) { int r = n-96;  if (r < 10 && k < 40) w = bW3[r*40+k]; }
        else if (n < 160) { int r = n-112; if (r < 41 && k < 41) w = sW1[r*41+k]; }
        else if (n < 208) { int r = n-160; if (r < 41 && k < 41) w = sW2[r*41+k]; }
        else              { int r = n-208; if (r < 22 && k < 41) w = sW3[r*41+k]; }
        unsigned short h = bf_rne(w);
        float hf = __builtin_bit_cast(float, ((unsigned)h) << 16);
        WH[i] = h; WL[i] = bf_rne(w - hf);
    } else if (i < 15600) {
        int n = i - 15360;
        float b;
        if      (n < 48)  b = (n     < 40) ? bb1[n]     : 0.f;
        else if (n < 96)  b = (n-48  < 40) ? bb2[n-48]  : 0.f;
        else if (n < 112) b = (n-96  < 10) ? bb3[n-96]  : -1e30f;
        else if (n < 160) b = (n-112 < 41) ? sb1[n-112] : 0.f;
        else if (n < 208) b = (n-160 < 41) ? sb2[n-160] : 0.f;
        else              b = (n-208 < 22) ? sb3[n-208] : -1e30f;
        BIAS[n] = b;
    }
}

// ---------- slot staging: 32 rows x 40 cols, coalesced float4, pre-split ----------
__device__ __forceinline__ void stage_load(const float* __restrict__ x, int R0, int S,
                                           int tid, float4* pf){
    #pragma unroll
    for (int it = 0; it < 3; ++it){
        int f = tid + TPB*it;
        if (f < 320){
            int r = f/10, c4 = f - r*10;
            pf[it] = *(const float4*)(x + (size_t)(R0+r)*XDIM + 40 + S*40 + c4*4);
        }
    }
}
__device__ __forceinline__ void stage_write(u32 (*xb)[XSW], const float* iap, int S,
                                            int tid, const float4* pf){
    #pragma unroll
    for (int it = 0; it < 3; ++it){
        int f = tid + TPB*it;
        if (f < 320){
            int r = f/10, c4 = f - r*10;
            uint4 pk;
            pk.x = packf(pf[it].x); pk.y = packf(pf[it].y);
            pk.z = packf(pf[it].z); pk.w = packf(pf[it].w);
            *(uint4*)&xb[r][4*c4] = pk;
        }
    }
    if (tid < RPB) xb[tid][40] = packf(iap[tid*10 + S]);   // iab input (k=40)
}

__global__ __launch_bounds__(TPB, 3) void ran2(
    const float* __restrict__ x,
    const unsigned short* __restrict__ WH,
    const unsigned short* __restrict__ WL,
    const float* __restrict__ BIAS,
    float* __restrict__ out)
{
    __shared__ u32   xsl[2][RPB][XSW];   // per-slot inputs, packed split, dbuf (13.0 KB)
    __shared__ u32   Act[RPB][AW];       // activations, packed split (8.5 KB)
    __shared__ float ia[RPB][10];        // big-net softmax (1.25 KB)
    // total 23.3 KB -> 6 blocks/CU (LDS-capped); VGPR cap 170 keeps weight hoist resident

    const int tid  = threadIdx.x;
    const int l    = tid & 63;
    const int w    = tid >> 6;
    const int q    = l >> 4;
    const int li   = l & 15;
    const int w16  = w * 16;
    const int R0   = blockIdx.x * RPB;
    const int arow = w16 + li;           // this lane's A-fragment row (local)

    // one-time zero of pad regions (xsl cols 40..51 both buffers; Act cols 48..67)
    for (int i = tid; i < 2*RPB*(XSW-40); i += TPB){
        int b = i / (RPB*(XSW-40)), k = i % (RPB*(XSW-40));
        xsl[b][k/(XSW-40)][40 + k%(XSW-40)] = 0u;
    }
    for (int i = tid; i < RPB*(AW-48); i += TPB)
        Act[i/(AW-48)][48 + i%(AW-48)] = 0u;
    __syncthreads();

    // ================= BIG NET (Act is wave-private: no barriers) =================
    {   // L1: x[:,0:40] -> Act
        s16x8 th[3][2], tl[3][2]; float tb[3];
        #pragma unroll
        for (int nt=0; nt<3; ++nt){
            tb[nt] = BIAS[nt*16+li];
            #pragma unroll
            for (int ks=0; ks<2; ++ks){
                th[nt][ks] = ld8u(WH + (nt*16+li)*64 + ks*32 + q*8);
                tl[nt][ks] = ld8u(WL + (nt*16+li)*64 + ks*32 + q*8);
            }
        }
        const float* xp = x + (size_t)(R0 + arow) * XDIM;
        float a0[8], a1[8];
        *(float4*)(a0)   = *(const float4*)(xp + q*8);
        *(float4*)(a0+4) = *(const float4*)(xp + q*8 + 4);
        if (q == 0){
            *(float4*)(a1)   = *(const float4*)(xp + 32);
            *(float4*)(a1+4) = *(const float4*)(xp + 36);
        } else {
            #pragma unroll
            for (int j=0;j<8;++j) a1[j] = 0.f;
        }
        s16x8 ah0,al0,ah1,al1;
        split8pk(a0, ah0, al0); split8pk(a1, ah1, al1);
        #pragma unroll
        for (int nt=0; nt<3; ++nt){
            f32x4 acc = {tb[nt],tb[nt],tb[nt],tb[nt]};
            acc = mm3(ah0,al0, th[nt][0], tl[nt][0], acc);
            acc = mm3(ah1,al1, th[nt][1], tl[nt][1], acc);
            #pragma unroll
            for (int r=0;r<4;++r)
                Act[w16+q*4+r][nt*16+li] = packf(fmaxf(acc[r],0.f));
        }
    }
    {   // L2: Act -> Act
        s16x8 th[3][2], tl[3][2]; float tb[3];
        #pragma unroll
        for (int nt=0; nt<3; ++nt){
            tb[nt] = BIAS[48+nt*16+li];
            #pragma unroll
            for (int ks=0; ks<2; ++ks){
                th[nt][ks] = ld8u(WH + (48+nt*16+li)*64 + ks*32 + q*8);
                tl[nt][ks] = ld8u(WL + (48+nt*16+li)*64 + ks*32 + q*8);
            }
        }
        s16x8 ah0,al0,ah1,al1;
        const u32* ap = &Act[arow][0];
        buildfrag(ap + q*8, ah0, al0);
        buildfrag(ap + 32 + q*8, ah1, al1);
        #pragma unroll
        for (int nt=0; nt<3; ++nt){
            f32x4 acc = {tb[nt],tb[nt],tb[nt],tb[nt]};
            acc = mm3(ah0,al0, th[nt][0], tl[nt][0], acc);
            acc = mm3(ah1,al1, th[nt][1], tl[nt][1], acc);
            #pragma unroll
            for (int r=0;r<4;++r)
                Act[w16+q*4+r][nt*16+li] = packf(fmaxf(acc[r],0.f));
        }
    }
    {   // L3 + softmax -> ia
        s16x8 th[2], tl[2]; float tb = BIAS[96+li];
        th[0] = ld8u(WH + (96+li)*64 + q*8);      tl[0] = ld8u(WL + (96+li)*64 + q*8);
        th[1] = ld8u(WH + (96+li)*64 + 32 + q*8); tl[1] = ld8u(WL + (96+li)*64 + 32 + q*8);
        s16x8 ah0,al0,ah1,al1;
        const u32* ap = &Act[arow][0];
        buildfrag(ap + q*8, ah0, al0);
        buildfrag(ap + 32 + q*8, ah1, al1);
        f32x4 acc = {tb,tb,tb,tb};
        acc = mm3(ah0,al0, th[0], tl[0], acc);
        acc = mm3(ah1,al1, th[1], tl[1], acc);
        #pragma unroll
        for (int r=0;r<4;++r){
            float v = acc[r];
            float m = v;
            m = fmaxf(m, __shfl_xor(m,1)); m = fmaxf(m, __shfl_xor(m,2));
            m = fmaxf(m, __shfl_xor(m,4)); m = fmaxf(m, __shfl_xor(m,8));
            float e = __expf(v - m);
            float sum = e;
            sum += __shfl_xor(sum,1); sum += __shfl_xor(sum,2);
            sum += __shfl_xor(sum,4); sum += __shfl_xor(sum,8);
            float p = __fdividef(e, sum);
            if (li < 10) ia[w16+q*4+r][li] = p;
        }
    }
    __syncthreads();   // ia visible (stage reads it cross-wave)

    // hoist small-net weights: 8 tiles x 2 ks x (h,l) = 128 VGPR, reused 10x
    s16x8 sh[8][2], sl[8][2]; float sb[8];
    {
        const int base[8] = {112,128,144, 160,176,192, 208,224};
        #pragma unroll
        for (int t2=0;t2<8;++t2){
            int n = base[t2] + li;
            sb[t2] = BIAS[n];
            #pragma unroll
            for (int ks=0;ks<2;++ks){
                sh[t2][ks] = ld8u(WH + n*64 + ks*32 + q*8);
                sl[t2][ks] = ld8u(WL + n*64 + ks*32 + q*8);
            }
        }
    }

    // stage slot 0
    {
        float4 pf[3];
        stage_load(x, R0, 0, tid, pf);
        stage_write(xsl[0], &ia[0][0], 0, tid, pf);
    }
    __syncthreads();

    // ================= SMALL NET: 10 slots, 1 barrier each =================
    int cur = 0;
    #pragma unroll 1
    for (int s = 0; s < 10; ++s){
        float4 pf[3];
        if (s < 9) stage_load(x, R0, s+1, tid, pf);      // early issue (T14)

        // ---- L1: xsl[cur] -> Act ----
        {
            s16x8 ah0,al0,ah1,al1;
            const u32* xr = &xsl[cur][arow][0];
            buildfrag(xr + q*8, ah0, al0);
            if (q < 2) buildfrag(xr + 32 + q*8, ah1, al1);
            else { uint4 z = {0,0,0,0}; ah1 = __builtin_bit_cast(s16x8, z); al1 = ah1; }
            #pragma unroll
            for (int nt=0; nt<3; ++nt){
                f32x4 acc = {sb[nt],sb[nt],sb[nt],sb[nt]};
                acc = mm3(ah0,al0, sh[nt][0], sl[nt][0], acc);
                acc = mm3(ah1,al1, sh[nt][1], sl[nt][1], acc);
                #pragma unroll
                for (int r=0;r<4;++r)
                    Act[w16+q*4+r][nt*16+li] = packf(fmaxf(acc[r],0.f));
            }
        }
        // write next slot's tile into the free buffer (hidden under compute)
        if (s < 9) stage_write(xsl[cur^1], &ia[0][0], s+1, tid, pf);

        // ---- L2: Act -> Act ----
        {
            s16x8 ah0,al0,ah1,al1;
            const u32* ap = &Act[arow][0];
            buildfrag(ap + q*8, ah0, al0);
            buildfrag(ap + 32 + q*8, ah1, al1);
            #pragma unroll
            for (int nt=0; nt<3; ++nt){
                f32x4 acc = {sb[3+nt],sb[3+nt],sb[3+nt],sb[3+nt]};
                acc = mm3(ah0,al0, sh[3+nt][0], sl[3+nt][0], acc);
                acc = mm3(ah1,al1, sh[3+nt][1], sl[3+nt][1], acc);
                #pragma unroll
                for (int r=0;r<4;++r)
                    Act[w16+q*4+r][nt*16+li] = packf(fmaxf(acc[r],0.f));
            }
        }
        // ---- L3 + softmax * iab -> direct global store ----
        {
            s16x8 ah0,al0,ah1,al1;
            const u32* ap = &Act[arow][0];
            buildfrag(ap + q*8, ah0, al0);
            buildfrag(ap + 32 + q*8, ah1, al1);
            f32x4 a6 = {sb[6],sb[6],sb[6],sb[6]};
            f32x4 a7 = {sb[7],sb[7],sb[7],sb[7]};
            a6 = mm3(ah0,al0, sh[6][0], sl[6][0], a6);
            a6 = mm3(ah1,al1, sh[6][1], sl[6][1], a6);
            a7 = mm3(ah0,al0, sh[7][0], sl[7][0], a7);
            a7 = mm3(ah1,al1, sh[7][1], sl[7][1], a7);
            #pragma unroll
            for (int r=0;r<4;++r){
                float v0 = a6[r], v1 = a7[r];
                float m = fmaxf(v0, v1);
                m = fmaxf(m, __shfl_xor(m,1)); m = fmaxf(m, __shfl_xor(m,2));
                m = fmaxf(m, __shfl_xor(m,4)); m = fmaxf(m, __shfl_xor(m,8));
                float e0 = __expf(v0 - m), e1 = __expf(v1 - m);
                float sum = e0 + e1;
                sum += __shfl_xor(sum,1); sum += __shfl_xor(sum,2);
                sum += __shfl_xor(sum,4); sum += __shfl_xor(sum,8);
                int lr = w16 + q*4 + r;
                float sc = __fdividef(ia[lr][s], sum);
                float* op = out + (size_t)(R0 + lr) * ODIM + s*22;
                op[li] = e0 * sc;
                if (li < 6) op[16 + li] = e1 * sc;
            }
        }
        __syncthreads();   // stage visible + Act epoch boundary
        cur ^= 1;
    }
}

extern "C" void kernel_launch(void* const* d_in, const int* in_sizes, int n_in,
                              void* d_out, int out_size, void* d_ws, size_t ws_size,
                              hipStream_t stream)
{
    (void)n_in; (void)out_size; (void)ws_size;
    const float* x   = (const float*)d_in[0];
    const float* bW1 = (const float*)d_in[1];
    const float* bb1 = (const float*)d_in[2];
    const float* bW2 = (const float*)d_in[3];
    const float* bb2 = (const float*)d_in[4];
    const float* bW3 = (const float*)d_in[5];
    const float* bb3 = (const float*)d_in[6];
    const float* sW1 = (const float*)d_in[7];
    const float* sb1 = (const float*)d_in[8];
    const float* sW2 = (const float*)d_in[9];
    const float* sb2 = (const float*)d_in[10];
    const float* sW3 = (const float*)d_in[11];
    const float* sb3 = (const float*)d_in[12];
    float* outp = (float*)d_out;

    unsigned short* WH = (unsigned short*)d_ws;
    unsigned short* WL = WH + 15360;
    float* BIAS = (float*)(WH + 30720);

    prep_w<<<61, 256, 0, stream>>>(bW1, bW2, bW3, sW1, sW2, sW3,
                                   bb1, bb2, bb3, sb1, sb2, sb3, WH, WL, BIAS);

    const int rows = in_sizes[0] / XDIM;            // 262144
    ran2<<<rows / RPB, TPB, 0, stream>>>(x, WH, WL, BIAS, outp);
}